// Round 5
// baseline (128.279 us; speedup 1.0000x reference)
//
#include <hip/hip_runtime.h>
#include <hip/hip_bf16.h>

typedef __bf16 bf16_t;
typedef bf16_t bf16x4 __attribute__((ext_vector_type(4)));
typedef bf16_t bf16x8 __attribute__((ext_vector_type(8)));
typedef float  f32x4  __attribute__((ext_vector_type(4)));

#define IN_F   1024
#define OUT_F  1024
#define RANK   8
#define NE     8
#define BATCH  32
#define SEQ    1024
#define M_TOT  (BATCH * SEQ)
#define SCALE  0.125f
#define NT     16   // K / 64

#define GLOAD_LDS16(g, l)                                                     \
  __builtin_amdgcn_global_load_lds(                                           \
      (const __attribute__((address_space(1))) void*)(g),                     \
      (__attribute__((address_space(3))) void*)(l), 16, 0, 0)

#define CFENCE asm volatile("" ::: "memory")
#define BAR()                                                                 \
  do { CFENCE; __builtin_amdgcn_s_barrier(); CFENCE; } while (0)
#define VMCNT(n) asm volatile("s_waitcnt vmcnt(" #n ")" ::: "memory")

// ---------------------------------------------------------------------------
// Kernel 1: W_eff[e][o][d] = bf16( W[o][d] + SCALE * sum_r Bw[e][o][r]*A[e][r][d] )
// ---------------------------------------------------------------------------
__global__ __launch_bounds__(256) void build_weff(
    const float* __restrict__ W, const float* __restrict__ A,
    const float* __restrict__ Bw, bf16_t* __restrict__ weff) {
  const int e  = blockIdx.x >> 10;
  const int o  = blockIdx.x & 1023;
  const int d0 = threadIdx.x << 2;

  f32x4 acc = *(const f32x4*)(W + ((size_t)o << 10) + d0);
  const float* bwr = Bw + (((size_t)e << 10) + o) * RANK;
  const float* ab  = A + (((size_t)e * RANK) << 10) + d0;
#pragma unroll
  for (int r = 0; r < RANK; ++r) {
    const float s = SCALE * bwr[r];
    const f32x4 a4 = *(const f32x4*)(ab + ((size_t)r << 10));
    acc += s * a4;
  }
  bf16x4 ov;
#pragma unroll
  for (int j = 0; j < 4; ++j) ov[j] = (bf16_t)acc[j];
  *(bf16x4*)(weff + (((size_t)e << 10) + o) * IN_F + d0) = ov;
}

// ---------------------------------------------------------------------------
// Kernel 2: x fp32 -> bf16
// ---------------------------------------------------------------------------
__global__ __launch_bounds__(256) void cvt_x(const float* __restrict__ x,
                                             bf16_t* __restrict__ xb, int n4) {
  int i = blockIdx.x * 256 + threadIdx.x;
  const int stride = gridDim.x * 256;
  for (; i < n4; i += stride) {
    const f32x4 v = *(const f32x4*)(x + ((size_t)i << 2));
    bf16x4 o;
#pragma unroll
    for (int j = 0; j < 4; ++j) o[j] = (bf16_t)v[j];
    *(bf16x4*)(xb + ((size_t)i << 2)) = o;
  }
}

// ---------------------------------------------------------------------------
// Kernel 3: 256x256 tile, BK=64, 8 waves (2M x 4N). ONE barrier per phase:
//   phase (j,kh): VMCNT(4); BAR; 12 ds_read_b128; stage (j+1,kh) [4
//   global_load_lds]; 32 MFMA (compiler-managed lgkmcnt -> reads of phase p
//   overlap MFMA drain of phase p-1; LDS pipe and MFMA pipe run parallel).
// WAR: stage(j+1,kh) targets region last read at phase (j-1,kh), >=1 barrier
// behind every wave. RAW: uniform VMCNT(4) retires exactly the 4 loads
// feeding this phase (stage-ahead = 1 phase), all-waves via the barrier.
// LDS swizzle identical to R2 (0 bank conflicts measured).
// ---------------------------------------------------------------------------
__global__ __launch_bounds__(512, 2) void gemm256(
    const bf16_t* __restrict__ xb, const bf16_t* __restrict__ weff,
    const float* __restrict__ bias, const int* __restrict__ sid,
    float* __restrict__ out) {
  __shared__ bf16_t lds[2][2][2][8192];  // [buf][A/B][kh][256x32] = 128 KiB

  const int bid0 = blockIdx.x;
  const int wgid = ((bid0 & 7) << 6) + (bid0 >> 3);  // XCD chunked (512 wgs)
  const int mb = wgid >> 2, nb = wgid & 3;
  const int m0 = mb << 8, n0 = nb << 8;
  const int e = sid[mb >> 2];

  const int tid = threadIdx.x;
  const int lane = tid & 63, wid = tid >> 6;
  const int wm = wid >> 2, wn = wid & 3;

  const bf16_t* agbase = xb + ((size_t)m0 << 10);
  const bf16_t* bgbase = weff + ((size_t)e << 20) + ((size_t)n0 << 10);

  // staging offsets: instr i covers LDS row r = wid*32 + i*16 + (lane>>2),
  // granule lane&3 (linear dest). Source granule pre-swizzled.
  int soff[2];
#pragma unroll
  for (int i = 0; i < 2; ++i) {
    const int r = (wid << 5) + (i << 4) + (lane >> 2);
    const int sg = (lane & 3) ^ ((r >> 1) & 3);
    soff[i] = (r << 10) + (sg << 3);
  }

  // fragment read offsets (swizzled), within one [256][32] kh tile
  int aoff[8], boff[4];
#pragma unroll
  for (int mi = 0; mi < 8; ++mi) {
    const int r = (wm << 7) + (mi << 4) + (lane & 15);
    const int g = (lane >> 4) ^ ((r >> 1) & 3);
    aoff[mi] = (r << 5) + (g << 3);
  }
#pragma unroll
  for (int ni = 0; ni < 4; ++ni) {
    const int r = (wn << 6) + (ni << 4) + (lane & 15);
    const int g = (lane >> 4) ^ ((r >> 1) & 3);
    boff[ni] = (r << 5) + (g << 3);
  }

  f32x4 acc[8][4] = {};

#define STAGE2(kt, kh)                                                        \
  do {                                                                        \
    bf16_t* _da = &lds[(kt) & 1][0][kh][wid << 10];                           \
    bf16_t* _db = &lds[(kt) & 1][1][kh][wid << 10];                           \
    const int _kc = ((kt) << 6) + ((kh) << 5);                                \
    GLOAD_LDS16(agbase + _kc + soff[0], _da);                                 \
    GLOAD_LDS16(agbase + _kc + soff[1], _da + 512);                           \
    GLOAD_LDS16(bgbase + _kc + soff[0], _db);                                 \
    GLOAD_LDS16(bgbase + _kc + soff[1], _db + 512);                           \
  } while (0)

#define PHASE_READS(kt, kh)                                                   \
  do {                                                                        \
    const bf16_t* _ab = &lds[(kt) & 1][0][kh][0];                             \
    const bf16_t* _bb = &lds[(kt) & 1][1][kh][0];                             \
    _Pragma("unroll") for (int mi = 0; mi < 8; ++mi)                          \
        af[mi] = *(const bf16x8*)(_ab + aoff[mi]);                            \
    _Pragma("unroll") for (int ni = 0; ni < 4; ++ni)                          \
        bfr[ni] = *(const bf16x8*)(_bb + boff[ni]);                           \
  } while (0)

#define MFMAS()                                                               \
  do {                                                                        \
    __builtin_amdgcn_s_setprio(1);                                            \
    _Pragma("unroll") for (int mi = 0; mi < 8; ++mi)                          \
        _Pragma("unroll") for (int ni = 0; ni < 4; ++ni)                      \
            acc[mi][ni] = __builtin_amdgcn_mfma_f32_16x16x32_bf16(            \
                af[mi], bfr[ni], acc[mi][ni], 0, 0, 0);                       \
    __builtin_amdgcn_s_setprio(0);                                            \
  } while (0)

  // prologue: stage phase-0 and phase-1 data (8 loads in flight)
  STAGE2(0, 0);
  STAGE2(0, 1);

  bf16x8 af[8], bfr[4];
  for (int j = 0; j < NT - 1; ++j) {
    // phase (j,0)
    VMCNT(4);            // retire stage2(j,0); keep stage2(j,1)
    BAR();
    PHASE_READS(j, 0);
    STAGE2(j + 1, 0);    // region last read at (j-1,0): >=1 barrier behind
    MFMAS();
    // phase (j,1)
    VMCNT(4);            // retire stage2(j,1); keep stage2(j+1,0)
    BAR();
    PHASE_READS(j, 1);
    STAGE2(j + 1, 1);
    MFMAS();
  }
  // tile NT-1: no more staging
  VMCNT(4);              // retire stage2(NT-1,0); keep stage2(NT-1,1)
  BAR();
  PHASE_READS(NT - 1, 0);
  MFMAS();
  VMCNT(0);              // retire stage2(NT-1,1)
  BAR();
  PHASE_READS(NT - 1, 1);
  MFMAS();

  // epilogue: C/D layout col=lane&15, row=(lane>>4)*4+j; nontemporal stores
  const int R0 = m0 + (wm << 7);
  const int C0 = n0 + (wn << 6);
  const int crow = (lane >> 4) << 2;
  const int ccol = lane & 15;
#pragma unroll
  for (int ni = 0; ni < 4; ++ni) {
    const int col = C0 + (ni << 4) + ccol;
    const float bv = bias[col];
#pragma unroll
    for (int mi = 0; mi < 8; ++mi) {
      const int row = R0 + (mi << 4) + crow;
#pragma unroll
      for (int j2 = 0; j2 < 4; ++j2)
        __builtin_nontemporal_store(acc[mi][ni][j2] + bv,
                                    &out[((size_t)(row + j2) << 10) + col]);
    }
  }
#undef STAGE2
#undef PHASE_READS
#undef MFMAS
}

// ---------------------------------------------------------------------------
// Fallback (ws too small): naive fp32.
// ---------------------------------------------------------------------------
__global__ __launch_bounds__(256) void lora_naive(
    const float* __restrict__ x, const float* __restrict__ W,
    const float* __restrict__ bias, const float* __restrict__ A,
    const float* __restrict__ Bw, const int* __restrict__ sid,
    float* __restrict__ out) {
  const int m = blockIdx.x;
  const int e = sid[m >> 10];
  __shared__ float xs[IN_F];
  __shared__ float h[RANK];
  const int tid = threadIdx.x;
  for (int i = tid; i < IN_F; i += 256) xs[i] = x[((size_t)m << 10) + i];
  __syncthreads();
  if (tid < RANK) {
    float s = 0.f;
    const float* ar = A + (((size_t)e * RANK + tid) << 10);
    for (int d = 0; d < IN_F; ++d) s += xs[d] * ar[d];
    h[tid] = s * SCALE;
  }
  __syncthreads();
  for (int o = tid; o < OUT_F; o += 256) {
    const float* wr = W + ((size_t)o << 10);
    float s = 0.f;
    for (int d = 0; d < IN_F; ++d) s += xs[d] * wr[d];
    const float* bwr = Bw + (((size_t)e << 10) + o) * RANK;
    float l = 0.f;
#pragma unroll
    for (int r = 0; r < RANK; ++r) l += h[r] * bwr[r];
    out[((size_t)m << 10) + o] = s + bias[o] + l;
  }
}

extern "C" void kernel_launch(void* const* d_in, const int* in_sizes, int n_in,
                              void* d_out, int out_size, void* d_ws,
                              size_t ws_size, hipStream_t stream) {
  const float* x   = (const float*)d_in[0];
  const float* W   = (const float*)d_in[1];
  const float* b   = (const float*)d_in[2];
  const float* A   = (const float*)d_in[3];
  const float* Bw  = (const float*)d_in[4];
  const int*   sid = (const int*)d_in[5];
  float* out = (float*)d_out;

  const size_t weff_bytes = (size_t)NE * OUT_F * IN_F * 2;  // 16 MiB
  const size_t xb_bytes   = (size_t)M_TOT * IN_F * 2;       // 64 MiB

  if (ws_size >= weff_bytes + xb_bytes) {
    bf16_t* weff = (bf16_t*)d_ws;
    bf16_t* xb   = (bf16_t*)((char*)d_ws + weff_bytes);
    hipLaunchKernelGGL(build_weff, dim3(NE * OUT_F), dim3(256), 0, stream,
                       W, A, Bw, weff);
    hipLaunchKernelGGL(cvt_x, dim3(4096), dim3(256), 0, stream,
                       x, xb, M_TOT * IN_F / 4);
    hipLaunchKernelGGL(gemm256, dim3((M_TOT / 256) * (OUT_F / 256)),
                       dim3(512), 0, stream, xb, weff, b, sid, out);
  } else {
    hipLaunchKernelGGL(lora_naive, dim3(M_TOT), dim3(256), 0, stream,
                       x, W, b, A, Bw, sid, out);
  }
}